// Round 2
// baseline (314.797 us; speedup 1.0000x reference)
//
#include <hip/hip_runtime.h>
#include <hip/hip_cooperative_groups.h>

namespace cg = cooperative_groups;

// QuantumRegressionModel: 16-qubit statevector, 3 layers x (16 rotations + CNOT chain),
// PauliZ features + linear head. Batch 64, DIM 65536, fp32.
//
// v3: single cooperative kernel (one dispatch, 6 grid.sync) using the v1 phase split:
//  * P-phase: wires 5..15 (bits 10..0). One wave = 2048-amp subcube, no LDS/barriers.
//    Register gates wires 5,6,7 (bits 10..8) + 14,15 (bits 1..0); shuffle gates 8..13 (bits 7..2).
//  * Q-phase: wires 0..4 (bits 15..11), 32 amps/thread, in-place, registers only.
//  * CNOT chain == Gray gather psi_new[j] = psi_old[j ^ (j>>1)] -> folded into next P-phase load.
//  * Features on pre-perm state via gray-decode signs, fused into final Q-phase.
//  * U built per-block in LDS (48 sincos) — no kPrep kernel; head fused at tail.
// Fallback: if 2 blocks/CU can't co-reside, launch the identical phases as separate kernels.
//
// Wire q <-> global index bit (15-q). State = separate re/im fp32 planes.

struct G8 { float r00,i00,r01,i01,r10,i10,r11,i11; };

__device__ __forceinline__ G8 loadG(const float* p) {
  G8 g;
  g.r00=p[0]; g.i00=p[1]; g.r01=p[2]; g.i01=p[3];
  g.r10=p[4]; g.i10=p[5]; g.r11=p[6]; g.i11=p[7];
  return g;
}

// complex 2x2: (x0,x1) <- U * (x0,x1)
__device__ __forceinline__ void cmul2(const G8& g, float& r0, float& i0, float& r1, float& i1) {
  const float nr0 = g.r00*r0 - g.i00*i0 + g.r01*r1 - g.i01*i1;
  const float ni0 = g.r00*i0 + g.i00*r0 + g.r01*i1 + g.i01*r1;
  const float nr1 = g.r10*r0 - g.i10*i0 + g.r11*r1 - g.i11*i1;
  const float ni1 = g.r10*i0 + g.i10*r0 + g.r11*i1 + g.i11*r1;
  r0=nr0; i0=ni0; r1=nr1; i1=ni1;
}

// Build the 48 fused unitaries U = Rz(tz)Ry(ty)Rx(tx) into U[384] (threads 0..47).
__device__ __forceinline__ void buildU(const float* __restrict__ vp, float* U) {
  const int i = threadIdx.x;
  if (i < 48) {
    const float tx = vp[i*6+0], ty = vp[i*6+1], tz = vp[i*6+2];
    float sx, cx, sy, cy, sz, cz;
    sincosf(0.5f*tx, &sx, &cx);
    sincosf(0.5f*ty, &sy, &cy);
    sincosf(0.5f*tz, &sz, &cz);
    const float m00r = cy*cx,  m00i = sy*sx;
    const float m01r = -sy*cx, m01i = -cy*sx;
    const float m10r = sy*cx,  m10i = -cy*sx;
    const float m11r = cy*cx,  m11i = -sy*sx;
    float* o = U + i*8;
    o[0] = cz*m00r + sz*m00i;  o[1] = cz*m00i - sz*m00r;
    o[2] = cz*m01r + sz*m01i;  o[3] = cz*m01i - sz*m01r;
    o[4] = cz*m10r - sz*m10i;  o[5] = cz*m10i + sz*m10r;
    o[6] = cz*m11r - sz*m11i;  o[7] = cz*m11i + sz*m11r;
  }
}

// P-phase body: wires 5..15 (bits 10..0). 512-block geometry: b = bx>>3, W = (bx&7)<<2 | wave.
// Per-thread bits {10..8}=k, {1,0}=e (float4 I/O); lane bits {7..2} -> shuffle gates.
// GATHER=1: fold previous layer's CNOT perm into the load: read src[g(j)], g(j)=j^(j>>1).
template<int GATHER>
__device__ __forceinline__ void pBody(const float* __restrict__ sr, const float* __restrict__ si,
                                      float* __restrict__ dr, float* __restrict__ di,
                                      const float* Ul, int t, int bx) {
  const int lane = t & 63;
  const int wv = t >> 6;
  const int b = bx >> 3;
  const int W = ((bx & 7) << 2) | wv;                  // bits 15..11
  const size_t bb = (size_t)b << 16;
  const int ebase = (W << 11) | (lane << 2);           // j with k=e=0
  float xr[32], xi[32];                                 // a = k*4 + e

  if (GATHER) {
    // g(j) permutes within the aligned float4: component = gray2(e) ^ (j2<<1), j2 = lane&1.
    const bool sw = (lane & 1);
    #pragma unroll
    for (int k = 0; k < 8; ++k) {
      const int base = ebase | (k << 8);
      const int a4 = (base ^ (base >> 1)) & ~3;
      const float4 vr = *(const float4*)(sr + bb + a4);
      const float4 vi = *(const float4*)(si + bb + a4);
      // gray2 = {0,1,3,2}; sw XORs component index with 2
      xr[k*4+0] = sw ? vr.z : vr.x;  xi[k*4+0] = sw ? vi.z : vi.x;
      xr[k*4+1] = sw ? vr.w : vr.y;  xi[k*4+1] = sw ? vi.w : vi.y;
      xr[k*4+2] = sw ? vr.y : vr.w;  xi[k*4+2] = sw ? vi.y : vi.w;
      xr[k*4+3] = sw ? vr.x : vr.z;  xi[k*4+3] = sw ? vi.x : vi.z;
    }
  } else {
    #pragma unroll
    for (int k = 0; k < 8; ++k) {
      const int base = ebase | (k << 8);
      const float4 vr = *(const float4*)(sr + bb + base);
      const float4 vi = *(const float4*)(si + bb + base);
      xr[k*4+0]=vr.x; xr[k*4+1]=vr.y; xr[k*4+2]=vr.z; xr[k*4+3]=vr.w;
      xi[k*4+0]=vi.x; xi[k*4+1]=vi.y; xi[k*4+2]=vi.z; xi[k*4+3]=vi.w;
    }
  }

  // Register gates on k bits: kb=2 -> bit10 -> wire5; kb=1 -> wire6; kb=0 -> wire7.
  #pragma unroll
  for (int g = 0; g < 3; ++g) {
    const int kb = 2 - g;
    const G8 U = loadG(Ul + (5 + g)*8);
    #pragma unroll
    for (int p = 0; p < 4; ++p) {
      const int k0 = ((p >> kb) << (kb + 1)) | (p & ((1 << kb) - 1));
      const int k1 = k0 | (1 << kb);
      #pragma unroll
      for (int e = 0; e < 4; ++e)
        cmul2(U, xr[k0*4+e], xi[k0*4+e], xr[k1*4+e], xi[k1*4+e]);
    }
  }

  // Shuffle gates on lane bits 5..0 -> bits 7..2 -> wires 8..13.
  #pragma unroll
  for (int g = 0; g < 6; ++g) {
    const int lb = 5 - g;
    const int mask = 1 << lb;
    const G8 U = loadG(Ul + (8 + g)*8);
    const bool hi = (lane >> lb) & 1;
    const float ar = hi ? U.r11 : U.r00, ai = hi ? U.i11 : U.i00;
    const float br = hi ? U.r10 : U.r01, bi = hi ? U.i10 : U.i01;
    #pragma unroll
    for (int a = 0; a < 32; ++a) {
      const float pr = __shfl_xor(xr[a], mask);
      const float pi_ = __shfl_xor(xi[a], mask);
      const float nr = ar*xr[a] - ai*xi[a] + br*pr - bi*pi_;
      const float ni = ar*xi[a] + ai*xr[a] + br*pi_ + bi*pr;
      xr[a] = nr; xi[a] = ni;
    }
  }

  // Register gates on e bits: bit1 -> wire14, bit0 -> wire15.
  {
    const G8 U = loadG(Ul + 14*8);
    #pragma unroll
    for (int k = 0; k < 8; ++k) {
      cmul2(U, xr[k*4+0], xi[k*4+0], xr[k*4+2], xi[k*4+2]);
      cmul2(U, xr[k*4+1], xi[k*4+1], xr[k*4+3], xi[k*4+3]);
    }
  }
  {
    const G8 U = loadG(Ul + 15*8);
    #pragma unroll
    for (int k = 0; k < 8; ++k) {
      cmul2(U, xr[k*4+0], xi[k*4+0], xr[k*4+1], xi[k*4+1]);
      cmul2(U, xr[k*4+2], xi[k*4+2], xr[k*4+3], xi[k*4+3]);
    }
  }

  #pragma unroll
  for (int k = 0; k < 8; ++k) {
    const int base = ebase | (k << 8);
    float4 vr, vi;
    vr.x=xr[k*4+0]; vr.y=xr[k*4+1]; vr.z=xr[k*4+2]; vr.w=xr[k*4+3];
    vi.x=xi[k*4+0]; vi.y=xi[k*4+1]; vi.z=xi[k*4+2]; vi.w=xi[k*4+3];
    *(float4*)(dr + bb + base) = vr;
    *(float4*)(di + bb + base) = vi;
  }
}

// Q-phase body: wires 0..4 (bits 15..11), 32 amps/thread, in-place, registers only.
// 512-block geometry: b = bx>>3, c = bx&7 (bits 10..8), t = bits 7..0.
__device__ __forceinline__ void qBody(float* __restrict__ r, float* __restrict__ im,
                                      const float* Ul, int t, int bx) {
  const int b = bx >> 3, c = bx & 7;
  const size_t base = ((size_t)b << 16) | (c << 8) | t;
  float xr[32], xi[32];
  #pragma unroll
  for (int k = 0; k < 32; ++k) { xr[k] = r[base + (k << 11)]; xi[k] = im[base + (k << 11)]; }
  #pragma unroll
  for (int g = 0; g < 5; ++g) {                        // wire g on k-bit 4-g (bit 15-g)
    const int kb = 4 - g;
    const G8 U = loadG(Ul + g*8);
    #pragma unroll
    for (int p = 0; p < 16; ++p) {
      const int i0 = ((p >> kb) << (kb + 1)) | (p & ((1 << kb) - 1));
      const int i1 = i0 | (1 << kb);
      cmul2(U, xr[i0], xi[i0], xr[i1], xi[i1]);
    }
  }
  #pragma unroll
  for (int k = 0; k < 32; ++k) { r[base + (k << 11)] = xr[k]; im[base + (k << 11)] = xi[k]; }
}

// Final Q-phase + fused PauliZ features (final CNOT perm folded via gray-decode signs).
// f_q = sum_m |amp(m)|^2 * (-1)^{parity(m >> (15-q))}.
__device__ __forceinline__ void qfBody(const float* __restrict__ r, const float* __restrict__ im,
                                       const float* Ul, float* __restrict__ feats, int t, int bx) {
  __shared__ float sf[64];
  const int b = bx >> 3, c = bx & 7;
  const size_t base = ((size_t)b << 16) | (c << 8) | t;
  float xr[32], xi[32];
  #pragma unroll
  for (int k = 0; k < 32; ++k) { xr[k] = r[base + (k << 11)]; xi[k] = im[base + (k << 11)]; }
  #pragma unroll
  for (int g = 0; g < 5; ++g) {
    const int kb = 4 - g;
    const G8 U = loadG(Ul + g*8);
    #pragma unroll
    for (int p = 0; p < 16; ++p) {
      const int i0 = ((p >> kb) << (kb + 1)) | (p & ((1 << kb) - 1));
      const int i1 = i0 | (1 << kb);
      cmul2(U, xr[i0], xi[i0], xr[i1], xi[i1]);
    }
  }
  // Signs for wires 0..4 depend only on k = m[15:11]; wires 5..15 = per-thread sign x S11.
  float S15=0.f, S14=0.f, S13=0.f, S12=0.f, S11=0.f;
  #pragma unroll
  for (int k = 0; k < 32; ++k) {
    const float p = xr[k]*xr[k] + xi[k]*xi[k];
    const int b4=(k>>4)&1, b3=(k>>3)&1, b2=(k>>2)&1, b1=(k>>1)&1, b0=k&1;
    S15 += b4 ? -p : p;
    S14 += (b4^b3) ? -p : p;
    S13 += (b4^b3^b2) ? -p : p;
    S12 += (b4^b3^b2^b1) ? -p : p;
    S11 += (b4^b3^b2^b1^b0) ? -p : p;
  }
  int v = (c << 8) | t;                       // gray-decode (suffix parity) of low 11 bits
  v ^= v >> 1; v ^= v >> 2; v ^= v >> 4; v ^= v >> 8;
  float f[16];
  f[0]=S15; f[1]=S14; f[2]=S13; f[3]=S12; f[4]=S11;
  #pragma unroll
  for (int q = 5; q < 16; ++q)
    f[q] = ((v >> (15 - q)) & 1) ? -S11 : S11;
  #pragma unroll
  for (int q = 0; q < 16; ++q) {
    float s = f[q];
    s += __shfl_xor(s, 32); s += __shfl_xor(s, 16); s += __shfl_xor(s, 8);
    s += __shfl_xor(s, 4);  s += __shfl_xor(s, 2);  s += __shfl_xor(s, 1);
    f[q] = s;
  }
  const int w = t >> 6;
  if ((t & 63) == 0) {
    #pragma unroll
    for (int q = 0; q < 16; ++q) sf[w*16 + q] = f[q];
  }
  __syncthreads();
  if (t < 16) {
    const float s = sf[t] + sf[16 + t] + sf[32 + t] + sf[48 + t];
    atomicAdd(&feats[b*16 + t], s);
  }
}

// ---- Single cooperative kernel: all 3 layers + features + head, 6 grid syncs. ----
__global__ void __launch_bounds__(256, 2) kAll(float* in_r, float* in_i,
                                               const float* __restrict__ vp,
                                               const float* __restrict__ hw,
                                               const float* __restrict__ hb,
                                               float* ws_r, float* ws_i,
                                               float* feats, float* out) {
  cg::grid_group grid = cg::this_grid();
  __shared__ float Ush[384];
  const int t = threadIdx.x;
  const int bx = blockIdx.x;
  buildU(vp, Ush);
  if (bx == 0) for (int j = t; j < 1024; j += 256) feats[j] = 0.f;
  __syncthreads();

  pBody<0>(in_r, in_i, ws_r, ws_i, Ush + 0*128, t, bx);      // layer 0: wires 5..15
  grid.sync();
  qBody(ws_r, ws_i, Ush + 0*128, t, bx);                     // layer 0: wires 0..4
  grid.sync();
  pBody<1>(ws_r, ws_i, in_r, in_i, Ush + 1*128, t, bx);      // layer 1 (+perm fold)
  grid.sync();
  qBody(in_r, in_i, Ush + 1*128, t, bx);
  grid.sync();
  pBody<1>(in_r, in_i, ws_r, ws_i, Ush + 2*128, t, bx);      // layer 2 (+perm fold)
  grid.sync();
  qfBody(ws_r, ws_i, Ush + 2*128, feats, t, bx);             // wires 0..4 + features
  grid.sync();

  if (bx == 0 && t < 64) {                                   // head
    float v = hb[0];
    #pragma unroll
    for (int q = 0; q < 16; ++q) v += feats[t*16 + q] * hw[q];
    out[t] = v;
  }
}

// ---- Fallback path: identical phases as separate kernels (if co-residency unavailable). ----
__global__ void kPrep(const float* __restrict__ vp, float* __restrict__ U,
                      float* __restrict__ feats) {
  __shared__ float Ush[384];
  buildU(vp, Ush);
  __syncthreads();
  const int i = threadIdx.x;
  for (int j = i; j < 384; j += 64) U[j] = Ush[j];
  for (int j = i; j < 1024; j += 64) feats[j] = 0.f;
}

template<int GATHER>
__global__ void __launch_bounds__(256) kP(const float* __restrict__ sr, const float* __restrict__ si,
                                          float* __restrict__ dr, float* __restrict__ di,
                                          const float* __restrict__ Ul) {
  pBody<GATHER>(sr, si, dr, di, Ul, threadIdx.x, blockIdx.x);
}

__global__ void __launch_bounds__(256) kQ(float* __restrict__ r, float* __restrict__ im,
                                          const float* __restrict__ Ul) {
  qBody(r, im, Ul, threadIdx.x, blockIdx.x);
}

__global__ void __launch_bounds__(256) kQF(const float* __restrict__ r, const float* __restrict__ im,
                                           const float* __restrict__ Ul, float* __restrict__ feats) {
  qfBody(r, im, Ul, feats, threadIdx.x, blockIdx.x);
}

__global__ void kHead(const float* __restrict__ feats, const float* __restrict__ w,
                      const float* __restrict__ bias, float* __restrict__ out) {
  const int b = threadIdx.x;
  if (b < 64) {
    float v = bias[0];
    #pragma unroll
    for (int q = 0; q < 16; ++q) v += feats[b*16 + q] * w[q];
    out[b] = v;
  }
}

extern "C" void kernel_launch(void* const* d_in, const int* in_sizes, int n_in,
                              void* d_out, int out_size, void* d_ws, size_t ws_size,
                              hipStream_t stream) {
  float* in_r = (float*)d_in[0];            // (64, 65536) fp32 — clobbered; harness restores
  float* in_i = (float*)d_in[1];
  const float* vp = (const float*)d_in[2];  // (3,16,6)
  const float* hw = (const float*)d_in[3];  // (1,16)
  const float* hb = (const float*)d_in[4];  // (1,)
  float* out = (float*)d_out;               // (64,) fp32

  float* ws_r  = (float*)d_ws;              // 4,194,304 floats
  float* ws_i  = ws_r + 4194304ull;
  float* Ubuf  = ws_i + 4194304ull;         // 48*8 floats
  float* feats = Ubuf + 384;                // 64*16 floats

  static int coopOk = -1;
  if (coopOk < 0) {
    int mb = 0;
    if (hipOccupancyMaxActiveBlocksPerMultiprocessor(&mb, kAll, 256, 0) != hipSuccess) mb = 0;
    coopOk = (mb >= 2) ? 1 : 0;   // need 512 blocks co-resident on 256 CUs
  }

  if (coopOk) {
    void* args[] = {(void*)&in_r, (void*)&in_i, (void*)&vp, (void*)&hw, (void*)&hb,
                    (void*)&ws_r, (void*)&ws_i, (void*)&feats, (void*)&out};
    hipLaunchCooperativeKernel(kAll, dim3(512), dim3(256), args, 0, stream);
  } else {
    kPrep<<<1, 64, 0, stream>>>(vp, Ubuf, feats);
    kP<0><<<512, 256, 0, stream>>>(in_r, in_i, ws_r, ws_i, Ubuf + 0*128);
    kQ   <<<512, 256, 0, stream>>>(ws_r, ws_i, Ubuf + 0*128);
    kP<1><<<512, 256, 0, stream>>>(ws_r, ws_i, in_r, in_i, Ubuf + 1*128);
    kQ   <<<512, 256, 0, stream>>>(in_r, in_i, Ubuf + 1*128);
    kP<1><<<512, 256, 0, stream>>>(in_r, in_i, ws_r, ws_i, Ubuf + 2*128);
    kQF  <<<512, 256, 0, stream>>>(ws_r, ws_i, Ubuf + 2*128, feats);
    kHead<<<1, 64, 0, stream>>>(feats, hw, hb, out);
  }
}

// Round 4
// 148.520 us; speedup vs baseline: 2.1196x; 2.1196x over previous
//
#include <hip/hip_runtime.h>

// QuantumRegressionModel: 16-qubit statevector, 3 layers x (16 rotations + CNOT chain),
// PauliZ features + linear head. Batch 64, DIM 65536, fp32.
//
// v5: ALGEBRAIC PERM FOLD, two passes (v4 with 3 ordering bugs fixed).
//   Full op = P*U2*P*U1*P*U0 = P^3 * (P^-2 U2 P^2) * (P^-1 U1 P) * U0, P = CNOT chain,
//   (P psi)[j] = psi[j ^ (j>>1)] (validated empirically in rounds 0-1).
//   Ũ1(b): acts bits {b,b-1}, row-select w(j)=parity(j>>b).
//   Ũ2(b'): acts bits {b',b'-2}, w(j)=parity over bits {b',b'+2,...}.
//   P^3 feature fold: sign_q(j) = parity(j & M(15-q)), M(b)=(0x3333<<b)&0xFFFF
//   (from (I+S)^-3 = sum C(k+2,2) S^k, nonzero iff k=0,1 mod 4).
//   Commutation (derived, drives the schedule):
//     U0(beta) ≺ Ũ1(b)  iff beta >= b-1;  U0(beta) ≺ Ũ2(b') iff beta=b'-2 or beta>=b' same parity;
//     Ũ1(b)   ≺ Ũ2(b') iff b >= b'-2;    Ũ1 adjacent desc;  Ũ2 chain desc by 2.
//   v4 bugs fixed: (1) Ũ1(11) was applied twice; (2) Ũ2(12) ran before Ũ1(10) (share bit 10)
//   -> pass A widened to bits {15..9} so Ũ1(10)+U0(wire6) live in pass A; (3) Ũ2(4) ran
//   before Ũ1(2) (share bit 2) -> Ũ2(4) moved to stage 3.
//   Pass A (kA), bits {15..9}: regs k=bits{15..11}; lane5=bit10, lane4=bit9.
//     U0 wires 0..6 (7), Ũ1 b=15..10 (6), Ũ2 b'=15..12 (4). in -> ws.  [17 gates]
//   Pass B (kB), bits {11..0}: 4096-amp blocks, h=bits{15..12}=blockIdx.
//     stage1 (regs kk=bits{11,10}, e=bits{1,0}; waves=bits{9,8}; lanes=bits{7..2}):
//       U0 wires 8..15 (bits 7..0). [8]
//     stage2 (retile: regs m=bits{11..8}; waves=bits{1,0}):
//       U0 wire7(bit8); Ũ1 b=9..3; Ũ2 b'=11..5. [15]
//     stage3 (retile back): Ũ1 b=2,1,0; Ũ2 b'=4..0; features+head fused. [8]
//   Total 48 gates; final state never stored.
// Wire q <-> bit (15-q). State = separate re/im fp32 planes.

struct G8 { float r00,i00,r01,i01,r10,i10,r11,i11; };

__device__ __forceinline__ G8 loadG(const float* p) {
  G8 g;
  g.r00=p[0]; g.i00=p[1]; g.r01=p[2]; g.i01=p[3];
  g.r10=p[4]; g.i10=p[5]; g.r11=p[6]; g.i11=p[7];
  return g;
}

// complex 2x2: (x0,x1) <- U * (x0,x1); first pair is the virtual-|0> slot.
__device__ __forceinline__ void cmul2(const G8& g, float& r0, float& i0, float& r1, float& i1) {
  const float nr0 = g.r00*r0 - g.i00*i0 + g.r01*r1 - g.i01*i1;
  const float ni0 = g.r00*i0 + g.i00*r0 + g.r01*i1 + g.i01*r1;
  const float nr1 = g.r10*r0 - g.i10*i0 + g.r11*r1 - g.i11*i1;
  const float ni1 = g.r10*i0 + g.i10*r0 + g.r11*i1 + g.i11*r1;
  r0=nr0; i0=ni0; r1=nr1; i1=ni1;
}

// ordered pair gate: flip=1 means the second element is the virtual-|0> slot.
__device__ __forceinline__ void cgate(const G8& g, int flip,
                                      float& r0, float& i0, float& r1, float& i1) {
  if (flip) cmul2(g, r1, i1, r0, i0);
  else      cmul2(g, r0, i0, r1, i1);
}

// per-amp update with partner p: new = D_w * x + O_w * p, w = virtual bit of this amp.
__device__ __forceinline__ void supd(const G8& g, int w, float& xr_, float& xi_,
                                     float pr, float pi_) {
  const float dr = w ? g.r11 : g.r00, di = w ? g.i11 : g.i00;
  const float br = w ? g.r10 : g.r01, bi = w ? g.i10 : g.i01;
  const float nr = dr*xr_ - di*xi_ + br*pr - bi*pi_;
  const float ni = dr*xi_ + di*xr_ + br*pi_ + bi*pr;
  xr_ = nr; xi_ = ni;
}

// Build the 48 fused unitaries U = Rz(tz)Ry(ty)Rx(tx) into U[384] (threads 0..47).
__device__ __forceinline__ void buildU(const float* __restrict__ vp, float* U) {
  const int i = threadIdx.x;
  if (i < 48) {
    const float tx = vp[i*6+0], ty = vp[i*6+1], tz = vp[i*6+2];
    float sx, cx, sy, cy, sz, cz;
    sincosf(0.5f*tx, &sx, &cx);
    sincosf(0.5f*ty, &sy, &cy);
    sincosf(0.5f*tz, &sz, &cz);
    const float m00r = cy*cx,  m00i = sy*sx;
    const float m01r = -sy*cx, m01i = -cy*sx;
    const float m10r = sy*cx,  m10i = -cy*sx;
    const float m11r = cy*cx,  m11i = -sy*sx;
    float* o = U + i*8;
    o[0] = cz*m00r + sz*m00i;  o[1] = cz*m00i - sz*m00r;
    o[2] = cz*m01r + sz*m01i;  o[3] = cz*m01i - sz*m01r;
    o[4] = cz*m10r - sz*m10i;  o[5] = cz*m10i + sz*m10r;
    o[6] = cz*m11r - sz*m11i;  o[7] = cz*m11i + sz*m11r;
  }
}

#define GU(l, w) loadG(Ush + ((l)*16 + (w))*8)

// ---------------- Pass A: bits {15..9} ------------------------------------
// j = k<<11 | l5<<10 | l4<<9 | c<<6 | wv<<4 | (l&15).  Grid: 64 batch x 8 c = 512 blocks.
__global__ void __launch_bounds__(256, 2)
kA(const float* __restrict__ sr, const float* __restrict__ si,
   float* __restrict__ dr, float* __restrict__ di,
   const float* __restrict__ vp, const float* __restrict__ hb, float* __restrict__ out) {
  __shared__ float Ush[384];
  buildU(vp, Ush);
  const int t = threadIdx.x;
  const int l = t & 63, wv = t >> 6;
  const int l5 = (l >> 5) & 1, l4 = (l >> 4) & 1;
  const int b = blockIdx.x >> 3, c = blockIdx.x & 7;
  if (blockIdx.x == 0 && t < 64) out[t] = hb[0];     // head bias init (kB atomicAdds later)
  __syncthreads();

  const size_t bb = (size_t)b << 16;
  const int tb = (l5 << 10) | (l4 << 9) | (c << 6) | (wv << 4) | (l & 15);
  float xr[32], xi[32];
  #pragma unroll
  for (int k = 0; k < 32; ++k) {
    xr[k] = sr[bb + (k << 11) + tb];
    xi[k] = si[bb + (k << 11) + tb];
  }

  // ---- U0 wires 0..4 on k-bits 4..0 (plain) ----
  #pragma unroll
  for (int g = 0; g < 5; ++g) {
    const int kb = 4 - g;                 // bit = 11+kb, wire = g
    const G8 U = GU(0, g);
    #pragma unroll
    for (int p = 0; p < 16; ++p) {
      const int i0 = ((p >> kb) << (kb + 1)) | (p & ((1 << kb) - 1));
      cmul2(U, xr[i0], xi[i0], xr[i0 | (1 << kb)], xi[i0 | (1 << kb)]);
    }
  }
  // ---- U0 wire 5 (bit10 = lane mask 32) ----
  { const G8 U = GU(0, 5);
    #pragma unroll
    for (int a = 0; a < 32; ++a) {
      const float pr = __shfl_xor(xr[a], 32), pi_ = __shfl_xor(xi[a], 32);
      supd(U, l5, xr[a], xi[a], pr, pi_);
    } }
  // ---- U0 wire 6 (bit9 = lane mask 16) ----
  { const G8 U = GU(0, 6);
    #pragma unroll
    for (int a = 0; a < 32; ++a) {
      const float pr = __shfl_xor(xr[a], 16), pi_ = __shfl_xor(xi[a], 16);
      supd(U, l4, xr[a], xi[a], pr, pi_);
    } }
  // ---- Ũ1 b=15: dir k{4,3} -> ^24, rep k4=0, flip 0 ----
  { const G8 U = GU(1, 0);
    #pragma unroll
    for (int k = 0; k < 32; ++k) if (!((k >> 4) & 1))
      cmul2(U, xr[k], xi[k], xr[k^24], xi[k^24]); }
  // ---- Ũ1 b=14: ^12, rep k3=0, flip k4 ----
  { const G8 U = GU(1, 1);
    #pragma unroll
    for (int k = 0; k < 32; ++k) if (!((k >> 3) & 1))
      cgate(U, (k >> 4) & 1, xr[k], xi[k], xr[k^12], xi[k^12]); }
  // ---- Ũ1 b=13: ^6, rep k2=0, flip k4^k3 ----
  { const G8 U = GU(1, 2);
    #pragma unroll
    for (int k = 0; k < 32; ++k) if (!((k >> 2) & 1))
      cgate(U, ((k>>4)^(k>>3)) & 1, xr[k], xi[k], xr[k^6], xi[k^6]); }
  // ---- Ũ1 b=12: ^3, rep k1=0, flip k4^k3^k2 ----
  { const G8 U = GU(1, 3);
    #pragma unroll
    for (int k = 0; k < 32; ++k) if (!((k >> 1) & 1))
      cgate(U, ((k>>4)^(k>>3)^(k>>2)) & 1, xr[k], xi[k], xr[k^3], xi[k^3]); }
  // ---- Ũ1 b=11: dir k0 x lane32; per-amp w = popc(k) ----
  { const G8 U = GU(1, 4);
    #pragma unroll
    for (int m = 0; m < 16; ++m) {
      const int k0 = 2*m, k1 = 2*m + 1;
      const float p0r = __shfl_xor(xr[k1], 32), p0i = __shfl_xor(xi[k1], 32);
      const float p1r = __shfl_xor(xr[k0], 32), p1i = __shfl_xor(xi[k0], 32);
      const int w0 = __builtin_popcount(k0) & 1;
      supd(U, w0,     xr[k0], xi[k0], p0r, p0i);
      supd(U, w0 ^ 1, xr[k1], xi[k1], p1r, p1i);
    } }
  // ---- Ũ1 b=10: dir lane{5,4} -> mask 48; per-amp w = popc(k)^l5 ----
  { const G8 U = GU(1, 5);
    #pragma unroll
    for (int k = 0; k < 32; ++k) {
      const float pr = __shfl_xor(xr[k], 48), pi_ = __shfl_xor(xi[k], 48);
      supd(U, (__builtin_popcount(k) ^ l5) & 1, xr[k], xi[k], pr, pi_);
    } }
  // ---- Ũ2 b'=15: dir k{4,2} -> ^20, rep k4=0, flip 0 ----
  { const G8 U = GU(2, 0);
    #pragma unroll
    for (int k = 0; k < 32; ++k) if (!((k >> 4) & 1))
      cmul2(U, xr[k], xi[k], xr[k^20], xi[k^20]); }
  // ---- Ũ2 b'=14: dir k{3,1} -> ^10, rep k3=0, flip 0 ----
  { const G8 U = GU(2, 1);
    #pragma unroll
    for (int k = 0; k < 32; ++k) if (!((k >> 3) & 1))
      cmul2(U, xr[k], xi[k], xr[k^10], xi[k^10]); }
  // ---- Ũ2 b'=13: dir k{2,0} -> ^5, rep k2=0, flip k4 ----
  { const G8 U = GU(2, 2);
    #pragma unroll
    for (int k = 0; k < 32; ++k) if (!((k >> 2) & 1))
      cgate(U, (k >> 4) & 1, xr[k], xi[k], xr[k^5], xi[k^5]); }
  // ---- Ũ2 b'=12: dir k1 x lane32; per-amp w = k1^k3 ----
  { const G8 U = GU(2, 3);
    #pragma unroll
    for (int k = 0; k < 32; ++k) if (!((k >> 1) & 1)) {
      const float p0r = __shfl_xor(xr[k^2], 32), p0i = __shfl_xor(xi[k^2], 32);
      const float p1r = __shfl_xor(xr[k],   32), p1i = __shfl_xor(xi[k],   32);
      const int w0 = (k >> 3) & 1;               // rep has k1=0
      supd(U, w0,     xr[k],   xi[k],   p0r, p0i);
      supd(U, w0 ^ 1, xr[k^2], xi[k^2], p1r, p1i);
    } }

  #pragma unroll
  for (int k = 0; k < 32; ++k) {
    dr[bb + (k << 11) + tb] = xr[k];
    di[bb + (k << 11) + tb] = xi[k];
  }
}

// ---------------- Pass B: bits {11..0} ------------------------------------
// Layout A: regs kk=bits{11,10}, e=bits{1,0} (16 amps, float4 I/O); lanes bits{7..2};
//           waves bits{9,8}. Grid: 64 batch x h=bits{15..12} -> 1024 blocks.
// Layout B2 (swizzled LDS retile, bits {9,8}<->{1,0}): regs m=bits{11..8}; waves bits{1,0}.
__device__ __forceinline__ int SA(int a) { return a ^ ((a >> 6) & 3); }  // 2-way max (free)

__global__ void __launch_bounds__(256, 2)
kB(const float* __restrict__ sr, const float* __restrict__ si,
   const float* __restrict__ vp, const float* __restrict__ hw, float* __restrict__ out) {
  __shared__ float lds[8192];
  __shared__ float Ush[384];
  __shared__ float red[4];
  buildU(vp, Ush);
  const int t = threadIdx.x;
  const int l = t & 63, wv = t >> 6;
  const int b = blockIdx.x >> 4, h = blockIdx.x & 15;
  __syncthreads();

  const int ph = __builtin_popcount(h) & 1;             // parity(bits 15..12)
  const int pA = ((h >> 1) ^ (h >> 3)) & 1;             // bit13 ^ bit15
  const int pB = (h ^ (h >> 2)) & 1;                    // bit12 ^ bit14
  const size_t base0 = ((size_t)b << 16) | (h << 12) | (wv << 8) | (l << 2);

  float xr[16], xi[16];                                  // a = kk*4 + e
  #pragma unroll
  for (int k = 0; k < 4; ++k) {
    const float4 vr = *(const float4*)(sr + base0 + (k << 10));
    const float4 vi = *(const float4*)(si + base0 + (k << 10));
    xr[k*4+0]=vr.x; xr[k*4+1]=vr.y; xr[k*4+2]=vr.z; xr[k*4+3]=vr.w;
    xi[k*4+0]=vi.x; xi[k*4+1]=vi.y; xi[k*4+2]=vi.z; xi[k*4+3]=vi.w;
  }

  // ======== Stage 1 (layout A): U0 bits 7..0 ========
  #pragma unroll
  for (int g = 0; g < 6; ++g) {                          // wires 8..13 = lane masks 32..1
    const int mask = 32 >> g;
    const G8 U = GU(0, 8 + g);
    const int hi = (l >> (5 - g)) & 1;
    #pragma unroll
    for (int a = 0; a < 16; ++a) {
      const float pr = __shfl_xor(xr[a], mask), pi_ = __shfl_xor(xi[a], mask);
      supd(U, hi, xr[a], xi[a], pr, pi_);
    }
  }
  { const G8 U = GU(0, 14);                              // wire 14 = bit1 = e1
    #pragma unroll
    for (int k = 0; k < 4; ++k) {
      cmul2(U, xr[k*4+0], xi[k*4+0], xr[k*4+2], xi[k*4+2]);
      cmul2(U, xr[k*4+1], xi[k*4+1], xr[k*4+3], xi[k*4+3]);
    } }
  { const G8 U = GU(0, 15);                              // wire 15 = bit0 = e0
    #pragma unroll
    for (int k = 0; k < 4; ++k) {
      cmul2(U, xr[k*4+0], xi[k*4+0], xr[k*4+1], xi[k*4+1]);
      cmul2(U, xr[k*4+2], xi[k*4+2], xr[k*4+3], xi[k*4+3]);
    } }

  // ---- retile A -> B2 ----
  #pragma unroll
  for (int k = 0; k < 4; ++k)
    #pragma unroll
    for (int e = 0; e < 4; ++e) {
      const int a = (k << 10) | (wv << 8) | (l << 2) | e;
      lds[SA(a)]        = xr[k*4+e];
      lds[4096 + SA(a)] = xi[k*4+e];
    }
  __syncthreads();
  float yr[16], yi[16];                                  // m = bits {11..8}
  #pragma unroll
  for (int m = 0; m < 16; ++m) {
    const int a2 = (m << 8) | (l << 2) | wv;
    yr[m] = lds[SA(a2)];
    yi[m] = lds[4096 + SA(a2)];
  }

  // ======== Stage 2 (layout B2) ========
  const int l5 = (l>>5)&1, l4 = (l>>4)&1, l3 = (l>>3)&1, l2 = (l>>2)&1, l1 = (l>>1)&1;
  { const G8 U = GU(0, 7);                               // U0 wire 7 = bit8 = m0
    #pragma unroll
    for (int m = 0; m < 16; ++m) if (!(m & 1))
      cmul2(U, yr[m], yi[m], yr[m^1], yi[m^1]); }
  // Ũ1 b=9 (w6): dir m{1,0} -> ^3; rep m1=0; flip = ph^m3^m2
  { const G8 U = GU(1, 6);
    #pragma unroll
    for (int m = 0; m < 16; ++m) if (!((m >> 1) & 1))
      cgate(U, ((m>>2) ^ (m>>3) ^ ph) & 1, yr[m], yi[m], yr[m^3], yi[m^3]); }
  // Ũ1 b=8 (w7): dir m0 x lane32; per-amp w = popc(m)^ph
  { const G8 U = GU(1, 7);
    #pragma unroll
    for (int m = 0; m < 16; m += 2) {
      const float p0r = __shfl_xor(yr[m+1], 32), p0i = __shfl_xor(yi[m+1], 32);
      const float p1r = __shfl_xor(yr[m],   32), p1i = __shfl_xor(yi[m],   32);
      const int w0 = (__builtin_popcount(m) ^ ph) & 1;
      supd(U, w0,     yr[m],   yi[m],   p0r, p0i);
      supd(U, w0 ^ 1, yr[m+1], yi[m+1], p1r, p1i);
    } }
  // Ũ1 b=7..3 (w8..12): pure-lane dirs, masks 48,24,12,6,3; w = lp ^ popc(m) ^ ph
  #pragma unroll
  for (int g = 0; g < 5; ++g) {
    const int mask = 48 >> g;
    const G8 U = GU(1, 8 + g);
    int lp;
    if      (g == 0) lp = l5;
    else if (g == 1) lp = l4 ^ l5;
    else if (g == 2) lp = l3 ^ l4 ^ l5;
    else if (g == 3) lp = l2 ^ l3 ^ l4 ^ l5;
    else             lp = l1 ^ l2 ^ l3 ^ l4 ^ l5;
    #pragma unroll
    for (int m = 0; m < 16; ++m) {
      const float pr = __shfl_xor(yr[m], mask), pi_ = __shfl_xor(yi[m], mask);
      supd(U, (lp ^ __builtin_popcount(m) ^ ph) & 1, yr[m], yi[m], pr, pi_);
    }
  }
  // Ũ2 b'=11 (w4): dir m{3,1} -> ^10; rep m3=0; flip = pA
  { const G8 U = GU(2, 4);
    #pragma unroll
    for (int m = 0; m < 16; ++m) if (!((m >> 3) & 1))
      cgate(U, pA, yr[m], yi[m], yr[m^10], yi[m^10]); }
  // Ũ2 b'=10 (w5): dir m{2,0} -> ^5; rep m2=0; flip = pB
  { const G8 U = GU(2, 5);
    #pragma unroll
    for (int m = 0; m < 16; ++m) if (!((m >> 2) & 1))
      cgate(U, pB, yr[m], yi[m], yr[m^5], yi[m^5]); }
  // Ũ2 b'=9 (w6): dir m1 x lane32; per-amp w = m1^m3^pA
  { const G8 U = GU(2, 6);
    #pragma unroll
    for (int m = 0; m < 16; ++m) if (!((m >> 1) & 1)) {
      const float p0r = __shfl_xor(yr[m^2], 32), p0i = __shfl_xor(yi[m^2], 32);
      const float p1r = __shfl_xor(yr[m],   32), p1i = __shfl_xor(yi[m],   32);
      const int w0 = ((m >> 3) ^ pA) & 1;        // rep has m1=0
      supd(U, w0,     yr[m],   yi[m],   p0r, p0i);
      supd(U, w0 ^ 1, yr[m^2], yi[m^2], p1r, p1i);
    } }
  // Ũ2 b'=8 (w7): dir m0 x lane16; per-amp w = m0^m2^pB
  { const G8 U = GU(2, 7);
    #pragma unroll
    for (int m = 0; m < 16; m += 2) {
      const float p0r = __shfl_xor(yr[m+1], 16), p0i = __shfl_xor(yi[m+1], 16);
      const float p1r = __shfl_xor(yr[m],   16), p1i = __shfl_xor(yi[m],   16);
      const int w0 = ((m >> 2) ^ pB) & 1;        // rep has m0=0
      supd(U, w0,     yr[m],   yi[m],   p0r, p0i);
      supd(U, w0 ^ 1, yr[m+1], yi[m+1], p1r, p1i);
    } }
  // Ũ2 b'=7,6,5 (w8,9,10): pure-lane masks 40,20,10
  #pragma unroll
  for (int g = 0; g < 3; ++g) {
    const int mask = (g == 0) ? 40 : (g == 1) ? 20 : 10;
    const G8 U = GU(2, 8 + g);
    int lp, mpar, hp;
    if      (g == 0) { lp = l5;      mpar = 0x0A; hp = pA; }   // w = l5 ^ m1^m3 ^ pA
    else if (g == 1) { lp = l4;      mpar = 0x05; hp = pB; }   // w = l4 ^ m0^m2 ^ pB
    else             { lp = l3 ^ l5; mpar = 0x0A; hp = pA; }   // w = l3^l5 ^ m1^m3 ^ pA
    #pragma unroll
    for (int m = 0; m < 16; ++m) {
      const float pr = __shfl_xor(yr[m], mask), pi_ = __shfl_xor(yi[m], mask);
      supd(U, (lp ^ __builtin_popcount(m & mpar) ^ hp) & 1, yr[m], yi[m], pr, pi_);
    }
  }

  // ---- retile B2 -> A ----
  __syncthreads();
  #pragma unroll
  for (int m = 0; m < 16; ++m) {
    const int a2 = (m << 8) | (l << 2) | wv;
    lds[SA(a2)]        = yr[m];
    lds[4096 + SA(a2)] = yi[m];
  }
  __syncthreads();
  #pragma unroll
  for (int k = 0; k < 4; ++k)
    #pragma unroll
    for (int e = 0; e < 4; ++e) {
      const int a = (k << 10) | (wv << 8) | (l << 2) | e;
      xr[k*4+e] = lds[SA(a)];
      xi[k*4+e] = lds[4096 + SA(a)];
    }

  // ======== Stage 3 (layout A) ========
  const int wv1 = (wv >> 1) & 1, wv0 = wv & 1;
  const int l0 = l & 1;
  const int RP   = (__builtin_popcount(l) ^ __builtin_popcount(wv) ^ ph) & 1;   // bits{2..9,12..15}
  const int oddT = (l1 ^ l3 ^ l5 ^ wv1 ^ pA) & 1;                               // bits{3,5,7,9,13,15}
  const int evT  = (l0 ^ l2 ^ l4 ^ wv0 ^ pB) & 1;                               // bits{2,4,6,8,12,14}
  // Ũ1 b=2 (w13): dir lane-mask1 x e1; per-amp w = RP ^ popc(kk)
  { const G8 U = GU(1, 13);
    #pragma unroll
    for (int k = 0; k < 4; ++k) {
      const int w = (RP ^ __builtin_popcount(k)) & 1;
      #pragma unroll
      for (int e0 = 0; e0 < 2; ++e0) {
        const int a = k*4 + e0, a2 = k*4 + e0 + 2;
        const float par = __shfl_xor(xr[a2], 1), pai = __shfl_xor(xi[a2], 1);
        const float pbr = __shfl_xor(xr[a],  1), pbi = __shfl_xor(xi[a],  1);
        supd(U, w, xr[a],  xi[a],  par, pai);
        supd(U, w, xr[a2], xi[a2], pbr, pbi);
      }
    } }
  // Ũ1 b=1 (w14): dir e{1,0} -> pairs (0,3),(1,2); rep e1=0; flip = RP ^ popc(kk)
  { const G8 U = GU(1, 14);
    #pragma unroll
    for (int k = 0; k < 4; ++k) {
      const int f = (RP ^ __builtin_popcount(k)) & 1;
      cgate(U, f, xr[k*4+0], xi[k*4+0], xr[k*4+3], xi[k*4+3]);
      cgate(U, f, xr[k*4+1], xi[k*4+1], xr[k*4+2], xi[k*4+2]);
    } }
  // Ũ1 b=0 (w15): dir e0; rep e0=0; flip = RP ^ popc(kk) ^ e1
  { const G8 U = GU(1, 15);
    #pragma unroll
    for (int k = 0; k < 4; ++k) {
      const int f = (RP ^ __builtin_popcount(k)) & 1;
      cgate(U, f,     xr[k*4+0], xi[k*4+0], xr[k*4+1], xi[k*4+1]);
      cgate(U, f ^ 1, xr[k*4+2], xi[k*4+2], xr[k*4+3], xi[k*4+3]);
    } }
  // Ũ2 b'=4 (w11): pure-lane mask 5 (bits 4,2); per-amp w = l2^l4^wv0^kk0^pB
  { const G8 U = GU(2, 11);
    const int base4 = (l2 ^ l4 ^ wv0 ^ pB) & 1;
    #pragma unroll
    for (int a = 0; a < 16; ++a) {
      const float pr = __shfl_xor(xr[a], 5), pi_ = __shfl_xor(xi[a], 5);
      supd(U, (base4 ^ (a >> 2)) & 1, xr[a], xi[a], pr, pi_);
    } }
  // Ũ2 b'=3 (w12): dir lane-mask2 x e1; per-amp w = oddT ^ kk1
  { const G8 U = GU(2, 12);
    #pragma unroll
    for (int k = 0; k < 4; ++k) {
      const int w = (oddT ^ (k >> 1)) & 1;
      #pragma unroll
      for (int e0 = 0; e0 < 2; ++e0) {
        const int a = k*4 + e0, a2 = k*4 + e0 + 2;
        const float par = __shfl_xor(xr[a2], 2), pai = __shfl_xor(xi[a2], 2);
        const float pbr = __shfl_xor(xr[a],  2), pbi = __shfl_xor(xi[a],  2);
        supd(U, w, xr[a],  xi[a],  par, pai);
        supd(U, w, xr[a2], xi[a2], pbr, pbi);
      }
    } }
  // Ũ2 b'=2 (w13): dir lane-mask1 x e0; per-amp w = evT ^ kk0
  { const G8 U = GU(2, 13);
    #pragma unroll
    for (int k = 0; k < 4; ++k) {
      const int w = (evT ^ k) & 1;
      #pragma unroll
      for (int e0 = 0; e0 < 4; e0 += 2) {
        const int a = k*4 + e0, a2 = k*4 + e0 + 1;
        const float par = __shfl_xor(xr[a2], 1), pai = __shfl_xor(xi[a2], 1);
        const float pbr = __shfl_xor(xr[a],  1), pbi = __shfl_xor(xi[a],  1);
        supd(U, w, xr[a],  xi[a],  par, pai);
        supd(U, w, xr[a2], xi[a2], pbr, pbi);
      }
    } }
  // Ũ2 b'=1 (w14): dir e1; rep e1=0; flip = oddT ^ kk1
  { const G8 U = GU(2, 14);
    #pragma unroll
    for (int k = 0; k < 4; ++k) {
      const int f = (oddT ^ (k >> 1)) & 1;
      cgate(U, f, xr[k*4+0], xi[k*4+0], xr[k*4+2], xi[k*4+2]);
      cgate(U, f, xr[k*4+1], xi[k*4+1], xr[k*4+3], xi[k*4+3]);
    } }
  // Ũ2 b'=0 (w15): dir e0; rep e0=0; flip = evT ^ kk0
  { const G8 U = GU(2, 15);
    #pragma unroll
    for (int k = 0; k < 4; ++k) {
      const int f = (evT ^ k) & 1;
      cgate(U, f, xr[k*4+0], xi[k*4+0], xr[k*4+1], xi[k*4+1]);
      cgate(U, f, xr[k*4+2], xi[k*4+2], xr[k*4+3], xi[k*4+3]);
    } }

  // ======== Features (P^3 fold) + head, fused ========
  // sign_q(j) = parity(j & M(15-q)), M(b) = (0x3333 << b) & 0xFFFF.
  float p_[16];
  #pragma unroll
  for (int a = 0; a < 16; ++a) p_[a] = xr[a]*xr[a] + xi[a]*xi[a];
  const int jloc = (h << 12) | (wv << 8) | (l << 2);
  float hsum = 0.f;
  #pragma unroll
  for (int q = 0; q < 16; ++q) {
    const int M = (0x3333 << (15 - q)) & 0xFFFF;
    float s = 0.f;
    #pragma unroll
    for (int k = 0; k < 4; ++k)
      #pragma unroll
      for (int e = 0; e < 4; ++e) {
        const int amp = (k << 10) | e;
        s += (__builtin_popcount(amp & M) & 1) ? -p_[k*4+e] : p_[k*4+e];
      }
    if (__builtin_popcount(jloc & M) & 1) s = -s;
    hsum += hw[q] * s;
  }
  #pragma unroll
  for (int o = 32; o >= 1; o >>= 1) hsum += __shfl_xor(hsum, o);
  __syncthreads();
  if ((t & 63) == 0) red[wv] = hsum;
  __syncthreads();
  if (t == 0) atomicAdd(out + b, red[0] + red[1] + red[2] + red[3]);
}

extern "C" void kernel_launch(void* const* d_in, const int* in_sizes, int n_in,
                              void* d_out, int out_size, void* d_ws, size_t ws_size,
                              hipStream_t stream) {
  const float* in_r = (const float*)d_in[0];  // (64, 65536) fp32
  const float* in_i = (const float*)d_in[1];
  const float* vp = (const float*)d_in[2];    // (3,16,6)
  const float* hw = (const float*)d_in[3];    // (1,16)
  const float* hb = (const float*)d_in[4];    // (1,)
  float* out = (float*)d_out;                 // (64,) fp32

  float* ws_r = (float*)d_ws;                 // 4,194,304 floats
  float* ws_i = ws_r + 4194304ull;

  kA<<<512,  256, 0, stream>>>(in_r, in_i, ws_r, ws_i, vp, hb, out);
  kB<<<1024, 256, 0, stream>>>(ws_r, ws_i, vp, hw, out);
}

// Round 5
// 141.456 us; speedup vs baseline: 2.2254x; 1.0499x over previous
//
#include <hip/hip_runtime.h>

// QuantumRegressionModel: 16-qubit statevector, 3 layers x (16 rotations + CNOT chain),
// PauliZ features + linear head. Batch 64, DIM 65536, fp32.
//
// v6 = v5 (algebraic perm fold, 2 passes, PROVEN schedule) + packed-FP32 (v_pk_fma_f32):
//  * kA (bits {15..9}): 15 gates (U0 w0..6, Ũ1 b=15..11, Ũ2 b'=15..13); Ũ1(10),Ũ2(12)
//    moved to kB (commutation re-verified: Ũ1(10)⟂Ũ2(13); both after kA's gates).
//    Complex (re,im) packed in float2; supdP = 4 pk-fma + swap-neg (folds to op_sel/neg).
//  * kB (bits {12..0}, 8192-amp blocks, grid 512): 33 gates in 3 stages; every register
//    slot packs over BIT 12 (halves r12=0/1) -> all gate math exact 2x via v_pk_fma.
//    Parities involving bit12 (ph, pB) become per-half coefficient pairs (C2), built once
//    per gate. Ũ2(12) (dir {12,10}) crosses the pack dim: partner = half-swapped m^4.
//    LDS retile in b64 (r12 interleaved at bit0), XOR-swizzled, <=2-way conflicts.
//  * Features: sign_q(j)=parity(j & M(15-q)), M=(0x3333<<b)&0xFFFF; bit12 term per-half.
// Wire q <-> bit (15-q). Gate formulas identical to v5 (hardware-verified), with
// ph -> (P, P^1) and pB -> (h14, h14^1) per packed half.

typedef float f2 __attribute__((ext_vector_type(2)));

struct G8 { float r00,i00,r01,i01,r10,i10,r11,i11; };

__device__ __forceinline__ f2 mkf2(float a, float b) { f2 r; r.x = a; r.y = b; return r; }
__device__ __forceinline__ f2 swp(f2 v) { f2 r; r.x = v.y; r.y = v.x; return r; }
__device__ __forceinline__ f2 sn(f2 v) { f2 r; r.x = -v.y; r.y = v.x; return r; }
__device__ __forceinline__ f2 shf2(f2 v, int mask) {
  return mkf2(__shfl_xor(v.x, mask), __shfl_xor(v.y, mask));
}

__device__ __forceinline__ G8 loadG(const float* p) {
  G8 g;
  g.r00=p[0]; g.i00=p[1]; g.r01=p[2]; g.i01=p[3];
  g.r10=p[4]; g.i10=p[5]; g.r11=p[6]; g.i11=p[7];
  return g;
}

// ---- kA packing: x = (re, im) in one f2; complex gate via pk-fma + swap-neg. ----
struct CP { f2 dr, di, br, bi; };   // broadcast coeffs for row w
__device__ __forceinline__ CP mkCP(const G8& g, int w) {
  CP c;
  const float a = w ? g.r11 : g.r00, b = w ? g.i11 : g.i00;
  const float p = w ? g.r10 : g.r01, q = w ? g.i10 : g.i01;
  c.dr = mkf2(a,a); c.di = mkf2(b,b); c.br = mkf2(p,p); c.bi = mkf2(q,q);
  return c;
}
// x <- d (*) x + b (*) p   (complex mul on packed (re,im))
__device__ __forceinline__ void supdP(const CP& c, f2& x, f2 p) {
  x = __builtin_elementwise_fma(c.dr, x,
       __builtin_elementwise_fma(c.di, sn(x),
        __builtin_elementwise_fma(c.br, p, c.bi * sn(p))));
}

// ---- kB packing: xr/xi hold (r12=0, r12=1) halves; coeffs may differ per half. ----
struct C2 { f2 dr, di, br, bi; };
__device__ __forceinline__ C2 mkC2(const G8& g, int wlo, int whi) {
  C2 c;
  c.dr = mkf2(wlo ? g.r11 : g.r00, whi ? g.r11 : g.r00);
  c.di = mkf2(wlo ? g.i11 : g.i00, whi ? g.i11 : g.i00);
  c.br = mkf2(wlo ? g.r10 : g.r01, whi ? g.r10 : g.r01);
  c.bi = mkf2(wlo ? g.i10 : g.i01, whi ? g.i10 : g.i01);
  return c;
}
// (xr,xi) <- D_w * x + O_w * p, per half
__device__ __forceinline__ void supd2(const C2& c, f2& xr, f2& xi, f2 pr, f2 pi) {
  f2 nr = __builtin_elementwise_fma(c.dr, xr,
           __builtin_elementwise_fma(c.di, -xi,
            __builtin_elementwise_fma(c.br, pr, c.bi * (-pi))));
  f2 ni = __builtin_elementwise_fma(c.dr, xi,
           __builtin_elementwise_fma(c.di, xr,
            __builtin_elementwise_fma(c.br, pi, c.bi * pr)));
  xr = nr; xi = ni;
}

__device__ __forceinline__ void buildU(const float* __restrict__ vp, float* U) {
  const int i = threadIdx.x;
  if (i < 48) {
    const float tx = vp[i*6+0], ty = vp[i*6+1], tz = vp[i*6+2];
    float sx, cx, sy, cy, sz, cz;
    sincosf(0.5f*tx, &sx, &cx);
    sincosf(0.5f*ty, &sy, &cy);
    sincosf(0.5f*tz, &sz, &cz);
    const float m00r = cy*cx,  m00i = sy*sx;
    const float m01r = -sy*cx, m01i = -cy*sx;
    const float m10r = sy*cx,  m10i = -cy*sx;
    const float m11r = cy*cx,  m11i = -sy*sx;
    float* o = U + i*8;
    o[0] = cz*m00r + sz*m00i;  o[1] = cz*m00i - sz*m00r;
    o[2] = cz*m01r + sz*m01i;  o[3] = cz*m01i - sz*m01r;
    o[4] = cz*m10r - sz*m10i;  o[5] = cz*m10i + sz*m10r;
    o[6] = cz*m11r - sz*m11i;  o[7] = cz*m11i + sz*m11r;
  }
}

#define GU(l, w) loadG(Ush + ((l)*16 + (w))*8)

// ---------------- Pass A: bits {15..9}, 15 gates, (re,im)-packed -------------
// j = k<<11 | l5<<10 | l4<<9 | c<<6 | wv<<4 | (l&15). Grid: 64 batch x 8 c.
__global__ void __launch_bounds__(256, 2)
kA(const float* __restrict__ sr, const float* __restrict__ si,
   float* __restrict__ dr, float* __restrict__ di,
   const float* __restrict__ vp, const float* __restrict__ hb, float* __restrict__ out) {
  __shared__ float Ush[384];
  buildU(vp, Ush);
  const int t = threadIdx.x;
  const int l = t & 63, wv = t >> 6;
  const int l5 = (l >> 5) & 1, l4 = (l >> 4) & 1;
  const int b = blockIdx.x >> 3, c = blockIdx.x & 7;
  if (blockIdx.x == 0 && t < 64) out[t] = hb[0];     // head bias init
  __syncthreads();

  const size_t bb = (size_t)b << 16;
  const int tb = (l5 << 10) | (l4 << 9) | (c << 6) | (wv << 4) | (l & 15);
  f2 x[32];
  #pragma unroll
  for (int k = 0; k < 32; ++k) {
    const size_t a = bb + (k << 11) + tb;
    x[k] = mkf2(sr[a], si[a]);
  }

#define RPA(CA, CB, A, B) { f2 tt = x[A]; supdP(CA, x[A], x[B]); supdP(CB, x[B], tt); }

  // U0 wires 0..4 on k-bits 4..0
  #pragma unroll
  for (int g = 0; g < 5; ++g) {
    const int kb = 4 - g;
    const G8 U = GU(0, g);
    const CP c0 = mkCP(U, 0), c1 = mkCP(U, 1);
    #pragma unroll
    for (int p = 0; p < 16; ++p) {
      const int i0 = ((p >> kb) << (kb + 1)) | (p & ((1 << kb) - 1));
      RPA(c0, c1, i0, i0 | (1 << kb));
    }
  }
  // U0 wire5 (bit10 = lane mask 32)
  { const G8 U = GU(0,5); const CP cc = mkCP(U, l5);
    #pragma unroll
    for (int a = 0; a < 32; ++a) supdP(cc, x[a], shf2(x[a], 32)); }
  // U0 wire6 (bit9 = lane mask 16)
  { const G8 U = GU(0,6); const CP cc = mkCP(U, l4);
    #pragma unroll
    for (int a = 0; a < 32; ++a) supdP(cc, x[a], shf2(x[a], 16)); }
  // Ũ1 b=15: ^24, rep k4=0, flip 0
  { const G8 U = GU(1,0); const CP c0 = mkCP(U,0), c1 = mkCP(U,1);
    #pragma unroll
    for (int k = 0; k < 32; ++k) if (!((k>>4)&1)) RPA(c0, c1, k, k^24); }
  // Ũ1 b=14: ^12, rep k3=0, flip k4
  { const G8 U = GU(1,1); const CP c0 = mkCP(U,0), c1 = mkCP(U,1);
    #pragma unroll
    for (int k = 0; k < 32; ++k) if (!((k>>3)&1)) {
      const int f = (k>>4)&1;
      RPA(f?c1:c0, f?c0:c1, k, k^12);
    } }
  // Ũ1 b=13: ^6, rep k2=0, flip k4^k3
  { const G8 U = GU(1,2); const CP c0 = mkCP(U,0), c1 = mkCP(U,1);
    #pragma unroll
    for (int k = 0; k < 32; ++k) if (!((k>>2)&1)) {
      const int f = ((k>>4)^(k>>3))&1;
      RPA(f?c1:c0, f?c0:c1, k, k^6);
    } }
  // Ũ1 b=12: ^3, rep k1=0, flip k4^k3^k2
  { const G8 U = GU(1,3); const CP c0 = mkCP(U,0), c1 = mkCP(U,1);
    #pragma unroll
    for (int k = 0; k < 32; ++k) if (!((k>>1)&1)) {
      const int f = ((k>>4)^(k>>3)^(k>>2))&1;
      RPA(f?c1:c0, f?c0:c1, k, k^3);
    } }
  // Ũ1 b=11: dir k0 x lane32; per-amp w = popc(k)
  { const G8 U = GU(1,4); const CP c0 = mkCP(U,0), c1 = mkCP(U,1);
    #pragma unroll
    for (int m = 0; m < 16; ++m) {
      const int k0 = 2*m, k1 = 2*m+1;
      f2 p0 = shf2(x[k1], 32), p1 = shf2(x[k0], 32);
      const int w0 = __builtin_popcount(k0)&1;
      supdP(w0?c1:c0, x[k0], p0);
      supdP(w0?c0:c1, x[k1], p1);
    } }
  // Ũ2 b'=15: ^20, rep k4=0, flip 0
  { const G8 U = GU(2,0); const CP c0 = mkCP(U,0), c1 = mkCP(U,1);
    #pragma unroll
    for (int k = 0; k < 32; ++k) if (!((k>>4)&1)) RPA(c0, c1, k, k^20); }
  // Ũ2 b'=14: ^10, rep k3=0, flip 0
  { const G8 U = GU(2,1); const CP c0 = mkCP(U,0), c1 = mkCP(U,1);
    #pragma unroll
    for (int k = 0; k < 32; ++k) if (!((k>>3)&1)) RPA(c0, c1, k, k^10); }
  // Ũ2 b'=13: ^5, rep k2=0, flip k4
  { const G8 U = GU(2,2); const CP c0 = mkCP(U,0), c1 = mkCP(U,1);
    #pragma unroll
    for (int k = 0; k < 32; ++k) if (!((k>>2)&1)) {
      const int f = (k>>4)&1;
      RPA(f?c1:c0, f?c0:c1, k, k^5);
    } }

  #pragma unroll
  for (int k = 0; k < 32; ++k) {
    const size_t a = bb + (k << 11) + tb;
    dr[a] = x[k].x; di[a] = x[k].y;
  }
#undef RPA
}

// ---------------- Pass B: bits {12..0}, 33 gates, bit12-packed ---------------
// Layout A (stages 1,3): slot s = kk*4+e (kk=bits{11,10}, e=bits{1,0}); halves r12.
//   lanes = bits {7..2}; waves = bits {9,8}. Grid: 64 batch x h3=bits{15..13}.
// Layout B2 (stage 2): slot m = bits {11..8}; waves = bits {1,0}.
// LDS float idx = (bits{11..0} << 1) | r12, XOR-swizzled; b64 (f2) accesses.
__device__ __forceinline__ int SA2(int i) { return i ^ (((i >> 5) & 7) << 1); }

__global__ void __launch_bounds__(256, 2)
kB(const float* __restrict__ sr, const float* __restrict__ si,
   const float* __restrict__ vp, const float* __restrict__ hw, float* __restrict__ out) {
  __shared__ float lds[16384];
  __shared__ float Ush[384];
  __shared__ float red[4];
  buildU(vp, Ush);
  const int t = threadIdx.x;
  const int l = t & 63, wv = t >> 6;
  const int b = blockIdx.x >> 3, h3 = blockIdx.x & 7;
  __syncthreads();

  const int P   = __builtin_popcount(h3) & 1;       // parity bits 15..13 (lo-half ph)
  const int h14 = (h3 >> 1) & 1;                    // bit14 (lo-half pB)
  const int pA  = (h3 ^ (h3 >> 2)) & 1;             // bit13 ^ bit15 (half-uniform)
  const size_t base0 = ((size_t)b << 16) | (h3 << 13) | (wv << 8) | (l << 2);

  f2 xr2[16], xi2[16];
  #pragma unroll
  for (int kk = 0; kk < 4; ++kk) {
    const float4 r0 = *(const float4*)(sr + base0 + (kk << 10));
    const float4 r1 = *(const float4*)(sr + base0 + (kk << 10) + 4096);
    const float4 i0 = *(const float4*)(si + base0 + (kk << 10));
    const float4 i1 = *(const float4*)(si + base0 + (kk << 10) + 4096);
    xr2[kk*4+0] = mkf2(r0.x, r1.x); xr2[kk*4+1] = mkf2(r0.y, r1.y);
    xr2[kk*4+2] = mkf2(r0.z, r1.z); xr2[kk*4+3] = mkf2(r0.w, r1.w);
    xi2[kk*4+0] = mkf2(i0.x, i1.x); xi2[kk*4+1] = mkf2(i0.y, i1.y);
    xi2[kk*4+2] = mkf2(i0.z, i1.z); xi2[kk*4+3] = mkf2(i0.w, i1.w);
  }

#define RP2(CA, CB, A, B) { f2 tr = xr2[A], ti = xi2[A]; \
    supd2(CA, xr2[A], xi2[A], xr2[B], xi2[B]); \
    supd2(CB, xr2[B], xi2[B], tr, ti); }

  // ======== Stage 1 (layout A): U0 bits 7..0 ========
  #pragma unroll
  for (int g = 0; g < 6; ++g) {                      // wires 8..13 = lane masks 32..1
    const int mask = 32 >> g;
    const G8 U = GU(0, 8 + g);
    const int hi = (l >> (5 - g)) & 1;
    const C2 cc = mkC2(U, hi, hi);
    #pragma unroll
    for (int s = 0; s < 16; ++s) {
      f2 pr = shf2(xr2[s], mask), pi = shf2(xi2[s], mask);
      supd2(cc, xr2[s], xi2[s], pr, pi);
    }
  }
  { const G8 U = GU(0,14);                           // wire 14 = bit1 = e1
    const C2 c0 = mkC2(U,0,0), c1 = mkC2(U,1,1);
    #pragma unroll
    for (int kk = 0; kk < 4; ++kk)
      #pragma unroll
      for (int e0 = 0; e0 < 2; ++e0) RP2(c0, c1, kk*4+e0, kk*4+e0+2); }
  { const G8 U = GU(0,15);                           // wire 15 = bit0 = e0
    const C2 c0 = mkC2(U,0,0), c1 = mkC2(U,1,1);
    #pragma unroll
    for (int kk = 0; kk < 4; ++kk) {
      RP2(c0, c1, kk*4+0, kk*4+1);
      RP2(c0, c1, kk*4+2, kk*4+3);
    } }

  // ---- retile A -> B2 (b64, swizzled) ----
  #pragma unroll
  for (int s = 0; s < 16; ++s) {
    const int i0 = (((s >> 2) << 10) | (wv << 8) | (l << 2) | (s & 3)) << 1;
    *(f2*)&lds[SA2(i0)] = xr2[s];
    *(f2*)&lds[8192 + SA2(i0)] = xi2[s];
  }
  __syncthreads();
  #pragma unroll
  for (int m = 0; m < 16; ++m) {
    const int i2 = (((m << 8) | (l << 2) | wv)) << 1;
    xr2[m] = *(f2*)&lds[SA2(i2)];
    xi2[m] = *(f2*)&lds[8192 + SA2(i2)];
  }

  // ======== Stage 2 (layout B2: m = bits{11..8}) ========
  const int l5=(l>>5)&1, l4=(l>>4)&1, l3=(l>>3)&1, l2=(l>>2)&1, l1=(l>>1)&1, l0=l&1;
  { const G8 U = GU(0,7);                            // U0 wire 7 = bit8 = m0
    const C2 c0 = mkC2(U,0,0), c1 = mkC2(U,1,1);
    #pragma unroll
    for (int m = 0; m < 16; m += 2) RP2(c0, c1, m, m^1); }
  // Ũ1 b=10 (w5): pairs m^6 (m{2,1}); w = P2 ^ m3 ^ m2
  { const G8 U = GU(1,5);
    const C2 cA = mkC2(U, P, P^1), cB = mkC2(U, P^1, P);
    #pragma unroll
    for (int m = 0; m < 16; ++m) if (!((m>>2)&1)) {
      const int f = (m>>3)&1;                        // m2=0 here
      RP2(f?cB:cA, f?cA:cB, m, m^6);
    } }
  // Ũ1 b=9 (w6): pairs m^3 (m{1,0}); w = P2 ^ m3 ^ m2 ^ m1
  { const G8 U = GU(1,6);
    const C2 cA = mkC2(U, P, P^1), cB = mkC2(U, P^1, P);
    #pragma unroll
    for (int m = 0; m < 16; ++m) if (!((m>>1)&1)) {
      const int f = ((m>>3)^(m>>2))&1;
      RP2(f?cB:cA, f?cA:cB, m, m^3);
    } }
  // Ũ1 b=8 (w7): dir m0 x lane32; w = P2 ^ popc(m)
  { const G8 U = GU(1,7);
    const C2 cA = mkC2(U, P, P^1), cB = mkC2(U, P^1, P);
    #pragma unroll
    for (int m = 0; m < 16; m += 2) {
      f2 p0r = shf2(xr2[m^1],32), p0i = shf2(xi2[m^1],32);
      f2 p1r = shf2(xr2[m],32),   p1i = shf2(xi2[m],32);
      const int f = __builtin_popcount(m)&1;
      supd2(f?cB:cA, xr2[m], xi2[m], p0r, p0i);
      supd2(f?cA:cB, xr2[m^1], xi2[m^1], p1r, p1i);
    } }
  // Ũ1 b=7..3 (w8..12): lane masks 48,24,12,6,3; w = lp ^ P2 ^ popc(m)
  #pragma unroll
  for (int g = 0; g < 5; ++g) {
    const int mask = 48 >> g;
    const G8 U = GU(1, 8 + g);
    const int lp = (g==0)? l5 : (g==1)? (l4^l5) : (g==2)? (l3^l4^l5)
                 : (g==3)? (l2^l3^l4^l5) : (l1^l2^l3^l4^l5);
    const C2 cA = mkC2(U, lp^P, lp^P^1), cB = mkC2(U, lp^P^1, lp^P);
    #pragma unroll
    for (int m = 0; m < 16; ++m) {
      f2 pr = shf2(xr2[m], mask), pi = shf2(xi2[m], mask);
      supd2((__builtin_popcount(m)&1)?cB:cA, xr2[m], xi2[m], pr, pi);
    }
  }
  // Ũ2 b'=12 (w3): dir {12,10} = r12 x m2 — crosses pack dim: partner = swp(m^4);
  // w = r12 ^ h14 -> same C2 for all amps.
  { const G8 U = GU(2,3);
    const C2 cc = mkC2(U, h14, h14^1);
    #pragma unroll
    for (int m = 0; m < 16; ++m) if (!((m>>2)&1)) {
      f2 tr = xr2[m], ti = xi2[m];
      supd2(cc, xr2[m], xi2[m], swp(xr2[m^4]), swp(xi2[m^4]));
      supd2(cc, xr2[m^4], xi2[m^4], swp(tr), swp(ti));
    } }
  // Ũ2 b'=11 (w4): pairs m^10 (m{3,1}); w = pA ^ m3
  { const G8 U = GU(2,4);
    const C2 cA = mkC2(U, pA, pA), cB = mkC2(U, pA^1, pA^1);
    #pragma unroll
    for (int m = 0; m < 16; ++m) if (!((m>>3)&1)) RP2(cA, cB, m, m^10); }
  // Ũ2 b'=10 (w5): pairs m^5 (m{2,0}); w = pB2 ^ m2
  { const G8 U = GU(2,5);
    const C2 cA = mkC2(U, h14, h14^1), cB = mkC2(U, h14^1, h14);
    #pragma unroll
    for (int m = 0; m < 16; ++m) if (!((m>>2)&1)) RP2(cA, cB, m, m^5); }
  // Ũ2 b'=9 (w6): dir m1 x lane32; w = pA ^ m1 ^ m3
  { const G8 U = GU(2,6);
    const C2 cA = mkC2(U, pA, pA), cB = mkC2(U, pA^1, pA^1);
    #pragma unroll
    for (int m = 0; m < 16; ++m) if (!((m>>1)&1)) {
      f2 p0r = shf2(xr2[m^2],32), p0i = shf2(xi2[m^2],32);
      f2 p1r = shf2(xr2[m],32),   p1i = shf2(xi2[m],32);
      const int f = (m>>3)&1;                        // m1=0 here
      supd2(f?cB:cA, xr2[m], xi2[m], p0r, p0i);
      supd2(f?cA:cB, xr2[m^2], xi2[m^2], p1r, p1i);
    } }
  // Ũ2 b'=8 (w7): dir m0 x lane16; w = pB2 ^ m0 ^ m2
  { const G8 U = GU(2,7);
    const C2 cA = mkC2(U, h14, h14^1), cB = mkC2(U, h14^1, h14);
    #pragma unroll
    for (int m = 0; m < 16; m += 2) {
      f2 p0r = shf2(xr2[m^1],16), p0i = shf2(xi2[m^1],16);
      f2 p1r = shf2(xr2[m],16),   p1i = shf2(xi2[m],16);
      const int f = (m>>2)&1;                        // m0=0 here
      supd2(f?cB:cA, xr2[m], xi2[m], p0r, p0i);
      supd2(f?cA:cB, xr2[m^1], xi2[m^1], p1r, p1i);
    } }
  // Ũ2 b'=7,6,5 (w8,9,10): lane masks 40,20,10
  #pragma unroll
  for (int g = 0; g < 3; ++g) {
    const int mask = (g == 0) ? 40 : (g == 1) ? 20 : 10;
    const G8 U = GU(2, 8 + g);
    int lp, mpar, blo, bhi;
    if      (g == 0) { lp = l5;      mpar = 0x0A; blo = lp^pA;  bhi = lp^pA; }
    else if (g == 1) { lp = l4;      mpar = 0x05; blo = lp^h14; bhi = lp^h14^1; }
    else             { lp = l3^l5;   mpar = 0x0A; blo = lp^pA;  bhi = lp^pA; }
    const C2 cA = mkC2(U, blo, bhi), cB = mkC2(U, blo^1, bhi^1);
    #pragma unroll
    for (int m = 0; m < 16; ++m) {
      f2 pr = shf2(xr2[m], mask), pi = shf2(xi2[m], mask);
      supd2((__builtin_popcount(m & mpar)&1)?cB:cA, xr2[m], xi2[m], pr, pi);
    }
  }

  // ---- retile B2 -> A ----
  __syncthreads();
  #pragma unroll
  for (int m = 0; m < 16; ++m) {
    const int i2 = (((m << 8) | (l << 2) | wv)) << 1;
    *(f2*)&lds[SA2(i2)] = xr2[m];
    *(f2*)&lds[8192 + SA2(i2)] = xi2[m];
  }
  __syncthreads();
  #pragma unroll
  for (int s = 0; s < 16; ++s) {
    const int i0 = (((s >> 2) << 10) | (wv << 8) | (l << 2) | (s & 3)) << 1;
    xr2[s] = *(f2*)&lds[SA2(i0)];
    xi2[s] = *(f2*)&lds[8192 + SA2(i0)];
  }

  // ======== Stage 3 (layout A) ========
  const int wv1 = (wv >> 1) & 1, wv0 = wv & 1;
  const int RPlo = (__builtin_popcount(l) ^ __builtin_popcount(wv) ^ P) & 1;
  const int oddT = (l1 ^ l3 ^ l5 ^ wv1 ^ pA) & 1;
  const int evlo = (l0 ^ l2 ^ l4 ^ wv0 ^ h14) & 1;
  // Ũ1 b=2 (w13): dir lane-mask1 x e1; w = RP2 ^ popc(kk)  (same for pair)
  { const G8 U = GU(1,13);
    const C2 cA = mkC2(U, RPlo, RPlo^1), cB = mkC2(U, RPlo^1, RPlo);
    #pragma unroll
    for (int kk = 0; kk < 4; ++kk) {
      const C2& cc = (__builtin_popcount(kk)&1) ? cB : cA;
      #pragma unroll
      for (int e0 = 0; e0 < 2; ++e0) {
        const int a = kk*4 + e0, a2 = a + 2;
        f2 par = shf2(xr2[a2],1), pai = shf2(xi2[a2],1);
        f2 pbr = shf2(xr2[a],1),  pbi = shf2(xi2[a],1);
        supd2(cc, xr2[a],  xi2[a],  par, pai);
        supd2(cc, xr2[a2], xi2[a2], pbr, pbi);
      }
    } }
  // Ũ1 b=1 (w14): pairs (0,3),(1,2); w = RP2 ^ popc(kk) ^ e1
  { const G8 U = GU(1,14);
    const C2 cA = mkC2(U, RPlo, RPlo^1), cB = mkC2(U, RPlo^1, RPlo);
    #pragma unroll
    for (int kk = 0; kk < 4; ++kk) {
      const int f = __builtin_popcount(kk)&1;
      RP2(f?cB:cA, f?cA:cB, kk*4+0, kk*4+3);
      RP2(f?cB:cA, f?cA:cB, kk*4+1, kk*4+2);
    } }
  // Ũ1 b=0 (w15): pairs s^1; w = RP2 ^ popc(kk) ^ e1 ^ e0
  { const G8 U = GU(1,15);
    const C2 cA = mkC2(U, RPlo, RPlo^1), cB = mkC2(U, RPlo^1, RPlo);
    #pragma unroll
    for (int kk = 0; kk < 4; ++kk) {
      const int f = __builtin_popcount(kk)&1;
      RP2(f?cB:cA, f?cA:cB, kk*4+0, kk*4+1);
      RP2(f?cA:cB, f?cB:cA, kk*4+2, kk*4+3);
    } }
  // Ũ2 b'=4 (w11): lane mask 5; w = ev2 ^ l2^l4... base4 = l2^l4^wv0 ^ pB2 ^ kk0
  { const G8 U = GU(2,11);
    const int b4 = (l2 ^ l4 ^ wv0) & 1;
    const C2 cA = mkC2(U, b4^h14, b4^h14^1), cB = mkC2(U, b4^h14^1, b4^h14);
    #pragma unroll
    for (int s = 0; s < 16; ++s) {
      f2 pr = shf2(xr2[s], 5), pi = shf2(xi2[s], 5);
      supd2(((s>>2)&1)?cB:cA, xr2[s], xi2[s], pr, pi);
    } }
  // Ũ2 b'=3 (w12): dir lane-mask2 x e1; w = oddT ^ kk1 (same for pair)
  { const G8 U = GU(2,12);
    const C2 cA = mkC2(U, oddT, oddT), cB = mkC2(U, oddT^1, oddT^1);
    #pragma unroll
    for (int kk = 0; kk < 4; ++kk) {
      const C2& cc = ((kk>>1)&1) ? cB : cA;
      #pragma unroll
      for (int e0 = 0; e0 < 2; ++e0) {
        const int a = kk*4 + e0, a2 = a + 2;
        f2 par = shf2(xr2[a2],2), pai = shf2(xi2[a2],2);
        f2 pbr = shf2(xr2[a],2),  pbi = shf2(xi2[a],2);
        supd2(cc, xr2[a],  xi2[a],  par, pai);
        supd2(cc, xr2[a2], xi2[a2], pbr, pbi);
      }
    } }
  // Ũ2 b'=2 (w13): dir lane-mask1 x e0; w = ev2 ^ kk0 (same for pair)
  { const G8 U = GU(2,13);
    const C2 cA = mkC2(U, evlo, evlo^1), cB = mkC2(U, evlo^1, evlo);
    #pragma unroll
    for (int kk = 0; kk < 4; ++kk) {
      const C2& cc = (kk&1) ? cB : cA;
      #pragma unroll
      for (int e0 = 0; e0 < 4; e0 += 2) {
        const int a = kk*4 + e0, a2 = a + 1;
        f2 par = shf2(xr2[a2],1), pai = shf2(xi2[a2],1);
        f2 pbr = shf2(xr2[a],1),  pbi = shf2(xi2[a],1);
        supd2(cc, xr2[a],  xi2[a],  par, pai);
        supd2(cc, xr2[a2], xi2[a2], pbr, pbi);
      }
    } }
  // Ũ2 b'=1 (w14): pairs s^2; w = oddT ^ kk1 ^ e1
  { const G8 U = GU(2,14);
    const C2 cA = mkC2(U, oddT, oddT), cB = mkC2(U, oddT^1, oddT^1);
    #pragma unroll
    for (int kk = 0; kk < 4; ++kk) {
      const int f = (kk>>1)&1;
      RP2(f?cB:cA, f?cA:cB, kk*4+0, kk*4+2);
      RP2(f?cB:cA, f?cA:cB, kk*4+1, kk*4+3);
    } }
  // Ũ2 b'=0 (w15): pairs s^1; w = ev2 ^ kk0 ^ e0
  { const G8 U = GU(2,15);
    const C2 cA = mkC2(U, evlo, evlo^1), cB = mkC2(U, evlo^1, evlo);
    #pragma unroll
    for (int kk = 0; kk < 4; ++kk) {
      const int f = kk&1;
      RP2(f?cB:cA, f?cA:cB, kk*4+0, kk*4+1);
      RP2(f?cB:cA, f?cA:cB, kk*4+2, kk*4+3);
    } }

  // ======== Features (P^3 fold, bit12 per-half) + head ========
  #pragma unroll
  for (int s = 0; s < 16; ++s)
    xr2[s] = xr2[s]*xr2[s] + xi2[s]*xi2[s];          // reuse as |amp|^2
  const int jloc = (h3 << 13) | (wv << 8) | (l << 2);
  float hsum = 0.f;
  #pragma unroll
  for (int q = 0; q < 16; ++q) {
    const int M = (0x3333 << (15 - q)) & 0xFFFF;
    f2 acc = mkf2(0.f, 0.f);
    #pragma unroll
    for (int s = 0; s < 16; ++s) {
      const int amp = ((s >> 2) << 10) | (s & 3);
      if (__builtin_popcount(amp & M) & 1) acc -= xr2[s]; else acc += xr2[s];
    }
    float sv = acc.x + (((M >> 12) & 1) ? -acc.y : acc.y);
    if (__builtin_popcount(jloc & M) & 1) sv = -sv;
    hsum += hw[q] * sv;
  }
  #pragma unroll
  for (int o = 32; o >= 1; o >>= 1) hsum += __shfl_xor(hsum, o);
  if ((t & 63) == 0) red[wv] = hsum;
  __syncthreads();
  if (t == 0) atomicAdd(out + b, red[0] + red[1] + red[2] + red[3]);
#undef RP2
}

extern "C" void kernel_launch(void* const* d_in, const int* in_sizes, int n_in,
                              void* d_out, int out_size, void* d_ws, size_t ws_size,
                              hipStream_t stream) {
  const float* in_r = (const float*)d_in[0];  // (64, 65536) fp32
  const float* in_i = (const float*)d_in[1];
  const float* vp = (const float*)d_in[2];    // (3,16,6)
  const float* hw = (const float*)d_in[3];    // (1,16)
  const float* hb = (const float*)d_in[4];    // (1,)
  float* out = (float*)d_out;                 // (64,) fp32

  float* ws_r = (float*)d_ws;                 // 4,194,304 floats
  float* ws_i = ws_r + 4194304ull;

  kA<<<512, 256, 0, stream>>>(in_r, in_i, ws_r, ws_i, vp, hb, out);
  kB<<<512, 256, 0, stream>>>(ws_r, ws_i, vp, hw, out);
}